// Round 7
// baseline (266.526 us; speedup 1.0000x reference)
//
#include <hip/hip_runtime.h>
#include <hip/hip_bf16.h>
#include <math.h>

// ---------------- problem constants ----------------
#define HW    3136        // 56*56
#define PADA  4624        // 68*68 padded plane (fp32 NCHW)
#define NT    49

// ---------------- workspace regions (float offsets) — proven extent ----------------
// R0: dec_up -> part0,part1 -> fmap_att
// R1: attb [4][49][3136]            (old fmap slot; fmap eliminated)
// R2: xpad fp32 [4][256][68][68]
// R3: c2wb bf16                     (k1 eliminated)
// R4: xcat bf16 [4][3136][512] -> part2,part3 -> x2 (+ attT bf16 in part3 slot)
// R5: c1wb bf16 -> part4
// R6: stats
// R7: xpadT bf16 [4][68][68][256]
// R8: wbf bf16 [128][12544]
#define R0 0u
#define R1 3211264u
#define R2 6422528u
#define R3 11157504u
#define R4 12763136u
#define R5 15974400u
#define R6 17580032u
#define R7 17580544u
#define R8 19948032u

typedef __attribute__((ext_vector_type(8))) short bf16x8;
typedef __attribute__((ext_vector_type(4))) float f32x4;

__device__ __forceinline__ void gll16(const void* g, void* l) {
    __builtin_amdgcn_global_load_lds((const __attribute__((address_space(1))) void*)g,
                                     (__attribute__((address_space(3))) void*)l, 16, 0, 0);
}

// ---------------- bilinear 2x upsample (align_corners=False) ----------------
__global__ void k_upsample(const float* __restrict__ src, float* __restrict__ dst)
{
    int j = blockIdx.x * 256 + threadIdx.x;
    int bc = j / HW;
    int p  = j - bc * HW;
    int h  = p / 56;
    int w  = p - h * 56;

    int ih0; float fh;
    if (h & 1) { ih0 = h >> 1;       fh = 0.25f; }
    else       { ih0 = (h >> 1) - 1; fh = 0.75f; }
    int ih1 = min(ih0 + 1, 27); ih0 = max(ih0, 0);
    int iw0; float fw;
    if (w & 1) { iw0 = w >> 1;       fw = 0.25f; }
    else       { iw0 = (w >> 1) - 1; fw = 0.75f; }
    int iw1 = min(iw0 + 1, 27); iw0 = max(iw0, 0);

    const float* s = src + (size_t)bc * 784;
    float v00 = s[ih0*28 + iw0], v01 = s[ih0*28 + iw1];
    float v10 = s[ih1*28 + iw0], v11 = s[ih1*28 + iw1];
    dst[j] = (1.f-fh)*((1.f-fw)*v00 + fw*v01) + fh*((1.f-fw)*v10 + fw*v11);
}

// ---------------- tiled NCHW fp32 -> NHWC bf16 transpose (validated) ----------------
__global__ __launch_bounds__(256) void k_t2nhwc(const float* __restrict__ src,
        __hip_bfloat16* __restrict__ dst, int kstride, int c_off)
{
    __shared__ float t[64][65];
    const int tid = threadIdx.x;
    const int p0 = blockIdx.x * 64;
    const int c0 = blockIdx.y * 64;
    const int b  = blockIdx.z;
    const int pl = tid & 63, cr = tid >> 6;
    #pragma unroll
    for (int i = 0; i < 16; ++i) {
        const int c = c0 + i*4 + cr;
        t[i*4+cr][pl] = src[((size_t)(b*256 + c)) * HW + p0 + pl];
    }
    __syncthreads();
    const int cl = tid & 63, pr = tid >> 6;
    #pragma unroll
    for (int i = 0; i < 16; ++i) {
        const int p = p0 + i*4 + pr;
        dst[((size_t)(b*HW + p)) * kstride + c_off + c0 + cl] = __float2bfloat16(t[cl][i*4+pr]);
    }
}

// ---------------- fp32 -> bf16 straight convert ----------------
__global__ void k_cvt(const float* __restrict__ s, __hip_bfloat16* __restrict__ d)
{
    int j = blockIdx.x * 256 + threadIdx.x;
    d[j] = __float2bfloat16(s[j]);
}

// ---------------- w1 [128][256][49] -> Wbf [oc][k=t*256+c] bf16, LDS transpose ----------------
__global__ __launch_bounds__(256) void k_w1bf2(const float* __restrict__ w1,
        __hip_bfloat16* __restrict__ wt)
{
    __shared__ float t[NT * 257];           // [t][c] with 257 stride (bank-conflict-free)
    const int tid = threadIdx.x;
    const int oc  = blockIdx.x;             // 128 blocks
    const float* src = w1 + (size_t)oc * 12544;
    #pragma unroll
    for (int i = 0; i < 49; ++i) {
        const int idx = i * 256 + tid;      // contiguous read over [c][t]
        const int c  = idx / 49;
        const int tt = idx - c * 49;
        t[tt * 257 + c] = src[idx];
    }
    __syncthreads();
    __hip_bfloat16* dst = wt + (size_t)oc * 12544;
    #pragma unroll
    for (int i = 0; i < 49; ++i)
        dst[i * 256 + tid] = __float2bfloat16(t[i * 257 + tid]);   // contiguous write
}

// ---------------- c1 MFMA GEMM: M=256, K=512; epilogue writes xpad (fp32) + xpadT (bf16) ----------------
__global__ __launch_bounds__(256, 2) void k_gemmc1(
    const __hip_bfloat16* __restrict__ A, const __hip_bfloat16* __restrict__ B0,
    const float* __restrict__ bias, float* __restrict__ Xpad,
    __hip_bfloat16* __restrict__ XpadT)
{
    __shared__ __hip_bfloat16 As[8192];   // [128][64]
    __shared__ __hip_bfloat16 Bs[8192];   // [128][64]
    const int tid  = threadIdx.x;
    const int w    = tid >> 6;
    const int lane = tid & 63;
    const int n0   = blockIdx.x * 128;
    const int m0   = blockIdx.y * 128;

    unsigned aoffs[4], boffs[4];
    void *adst[4], *bdst[4];
    #pragma unroll
    for (int j = 0; j < 4; ++j) {
        const int slot = (w*4 + j)*64 + lane;
        const int row  = slot >> 3;
        const int q    = slot & 7;
        const int lc   = q ^ (row & 7);
        aoffs[j] = (unsigned)(m0 + row) * 512u + (unsigned)lc * 8u;
        adst[j]  = (void*)&As[(w*4 + j) * 512];
        boffs[j] = (unsigned)(n0 + row) * 512u + (unsigned)lc * 8u;
        bdst[j]  = (void*)&Bs[(w*4 + j) * 512];
    }

    const int l15 = lane & 15, lg = lane >> 4;
    const int m_w0 = (w & 1) * 64;
    const int n_w0 = (w >> 1) * 64;
    int rowA[4], rowB[4], chunkoff[2];
    #pragma unroll
    for (int i = 0; i < 4; ++i) {
        rowA[i] = (m_w0 + i*16 + l15) * 128;
        rowB[i] = (n_w0 + i*16 + l15) * 128;
    }
    #pragma unroll
    for (int ks = 0; ks < 2; ++ks)
        chunkoff[ks] = ((4*ks + lg) ^ (lane & 7)) * 16;

    f32x4 acc[4][4];
    #pragma unroll
    for (int i = 0; i < 4; ++i)
        #pragma unroll
        for (int j = 0; j < 4; ++j)
            acc[i][j] = (f32x4){0.f, 0.f, 0.f, 0.f};

    for (int k0 = 0; k0 < 512; k0 += 64) {
        #pragma unroll
        for (int j = 0; j < 4; ++j) gll16(A + aoffs[j] + k0, adst[j]);
        #pragma unroll
        for (int j = 0; j < 4; ++j) gll16(B0 + boffs[j] + k0, bdst[j]);
        __syncthreads();
        #pragma unroll
        for (int ks = 0; ks < 2; ++ks) {
            const int co = chunkoff[ks];
            bf16x8 av[4], bv[4];
            #pragma unroll
            for (int i = 0; i < 4; ++i)
                av[i] = *(const bf16x8*)((const char*)As + rowA[i] + co);
            #pragma unroll
            for (int i = 0; i < 4; ++i)
                bv[i] = *(const bf16x8*)((const char*)Bs + rowB[i] + co);
            #pragma unroll
            for (int i = 0; i < 4; ++i)
                #pragma unroll
                for (int j = 0; j < 4; ++j)
                    acc[i][j] = __builtin_amdgcn_mfma_f32_16x16x32_bf16(av[i], bv[j], acc[i][j], 0, 0, 0);
        }
        __syncthreads();
    }

    // epilogue: bias + relu, write fp32 NCHW-padded and bf16 NHWC-padded
    #pragma unroll
    for (int j = 0; j < 4; ++j) {
        const int n = n0 + n_w0 + j*16 + l15;
        const int b = n / HW;
        const int p = n - b * HW;
        const int h = p / 56;
        const int ww = p - h * 56;
        #pragma unroll
        for (int i = 0; i < 4; ++i) {
            const int m = m0 + m_w0 + i*16 + lg*4;
            const float4 bs4 = *(const float4*)&bias[m];
            float v0 = fmaxf(acc[i][j][0] + bs4.x, 0.f);
            float v1 = fmaxf(acc[i][j][1] + bs4.y, 0.f);
            float v2 = fmaxf(acc[i][j][2] + bs4.z, 0.f);
            float v3 = fmaxf(acc[i][j][3] + bs4.w, 0.f);
            float* dp = Xpad + ((size_t)(b*256 + m)) * PADA + (h + 6) * 68 + (ww + 6);
            dp[0]      = v0;
            dp[PADA]   = v1;
            dp[2*PADA] = v2;
            dp[3*PADA] = v3;
            ushort4 pk;
            pk.x = __bfloat16_as_ushort(__float2bfloat16(v0));
            pk.y = __bfloat16_as_ushort(__float2bfloat16(v1));
            pk.z = __bfloat16_as_ushort(__float2bfloat16(v2));
            pk.w = __bfloat16_as_ushort(__float2bfloat16(v3));
            *(ushort4*)(XpadT + ((size_t)((b*68 + h + 6)*68 + ww + 6)) * 256 + m) = pk;
        }
    }
}

// ---------------- c2 MFMA GEMM: M=128, K=512; B k<256 from xpadT center, k>=256 from attT ----------------
__global__ __launch_bounds__(256, 2) void k_gemmc2(
    const __hip_bfloat16* __restrict__ A, const __hip_bfloat16* __restrict__ XT,
    const __hip_bfloat16* __restrict__ AT, const float* __restrict__ bias,
    float* __restrict__ Y)
{
    __shared__ __hip_bfloat16 As[8192];
    __shared__ __hip_bfloat16 Bs[8192];
    const int tid  = threadIdx.x;
    const int w    = tid >> 6;
    const int lane = tid & 63;
    const int n0   = blockIdx.x * 128;

    unsigned aoffs[4], boffs0[4], boffs1[4];
    void *adst[4], *bdst[4];
    #pragma unroll
    for (int j = 0; j < 4; ++j) {
        const int slot = (w*4 + j)*64 + lane;
        const int row  = slot >> 3;
        const int q    = slot & 7;
        const int lc   = q ^ (row & 7);
        aoffs[j] = (unsigned)row * 512u + (unsigned)lc * 8u;
        adst[j]  = (void*)&As[(w*4 + j) * 512];
        const int n = n0 + row;
        const int b = n / HW;
        const int p = n - b * HW;
        const int h = p / 56;
        const int ww = p - h * 56;
        boffs0[j] = ((unsigned)(b*68 + h + 6)*68 + (unsigned)(ww + 6))*256u + (unsigned)lc * 8u;
        boffs1[j] = (unsigned)n * 256u + (unsigned)lc * 8u;
        bdst[j]  = (void*)&Bs[(w*4 + j) * 512];
    }

    const int l15 = lane & 15, lg = lane >> 4;
    const int m_w0 = (w & 1) * 64;
    const int n_w0 = (w >> 1) * 64;
    int rowA[4], rowB[4], chunkoff[2];
    #pragma unroll
    for (int i = 0; i < 4; ++i) {
        rowA[i] = (m_w0 + i*16 + l15) * 128;
        rowB[i] = (n_w0 + i*16 + l15) * 128;
    }
    #pragma unroll
    for (int ks = 0; ks < 2; ++ks)
        chunkoff[ks] = ((4*ks + lg) ^ (lane & 7)) * 16;

    f32x4 acc[4][4];
    #pragma unroll
    for (int i = 0; i < 4; ++i)
        #pragma unroll
        for (int j = 0; j < 4; ++j)
            acc[i][j] = (f32x4){0.f, 0.f, 0.f, 0.f};

    for (int k0 = 0; k0 < 512; k0 += 64) {
        #pragma unroll
        for (int j = 0; j < 4; ++j) gll16(A + aoffs[j] + k0, adst[j]);
        if (k0 < 256) {
            #pragma unroll
            for (int j = 0; j < 4; ++j) gll16(XT + boffs0[j] + k0, bdst[j]);
        } else {
            #pragma unroll
            for (int j = 0; j < 4; ++j) gll16(AT + boffs1[j] + (k0 - 256), bdst[j]);
        }
        __syncthreads();
        #pragma unroll
        for (int ks = 0; ks < 2; ++ks) {
            const int co = chunkoff[ks];
            bf16x8 av[4], bv[4];
            #pragma unroll
            for (int i = 0; i < 4; ++i)
                av[i] = *(const bf16x8*)((const char*)As + rowA[i] + co);
            #pragma unroll
            for (int i = 0; i < 4; ++i)
                bv[i] = *(const bf16x8*)((const char*)Bs + rowB[i] + co);
            #pragma unroll
            for (int i = 0; i < 4; ++i)
                #pragma unroll
                for (int j = 0; j < 4; ++j)
                    acc[i][j] = __builtin_amdgcn_mfma_f32_16x16x32_bf16(av[i], bv[j], acc[i][j], 0, 0, 0);
        }
        __syncthreads();
    }

    #pragma unroll
    for (int j = 0; j < 4; ++j) {
        const int n = n0 + n_w0 + j*16 + l15;
        const int b = n / HW;
        const int p = n - b * HW;
        #pragma unroll
        for (int i = 0; i < 4; ++i) {
            const int m = m_w0 + i*16 + lg*4;
            const float4 bs4 = *(const float4*)&bias[m];
            float* dst = Y + ((size_t)(b*128 + m) * HW + p);
            dst[0]    = acc[i][j][0] + bs4.x;
            dst[HW]   = acc[i][j][1] + bs4.y;
            dst[2*HW] = acc[i][j][2] + bs4.z;
            dst[3*HW] = acc[i][j][3] + bs4.w;
        }
    }
}

// ---------------- dilated 7x7 conv: bf16 MFMA implicit GEMM, K-split x5 (validated) ----------------
__global__ __launch_bounds__(256, 2) void k_convmfma(
    const __hip_bfloat16* __restrict__ Wbf, const __hip_bfloat16* __restrict__ XT,
    float* __restrict__ o0, float* __restrict__ o1, float* __restrict__ o2,
    float* __restrict__ o3, float* __restrict__ o4)
{
    __shared__ __hip_bfloat16 As[8192];
    __shared__ __hip_bfloat16 Bs[8192];
    const int tid  = threadIdx.x;
    const int w    = tid >> 6;
    const int lane = tid & 63;
    const int n0   = blockIdx.x * 128;
    const int s    = blockIdx.y;
    const int t_start = (s < 4) ? s * 40 : 158;
    const int cnt     = (s < 3) ? 40 : 38;
    float* __restrict__ out = (s==0)?o0:(s==1)?o1:(s==2)?o2:(s==3)?o3:o4;

    unsigned aoffs[4], boffs[4];
    void *adst[4], *bdst[4];
    #pragma unroll
    for (int j = 0; j < 4; ++j) {
        const int slot = (w*4 + j)*64 + lane;
        const int row  = slot >> 3;
        const int q    = slot & 7;
        const int lc   = q ^ (row & 7);
        aoffs[j] = (unsigned)row * 12544u + (unsigned)lc * 8u;
        adst[j]  = (void*)&As[(w*4 + j) * 512];
        const int n = n0 + row;
        const int b = n / HW;
        const int p = n - b * HW;
        const int h = p / 56;
        const int ww = p - h * 56;
        boffs[j] = ((unsigned)(b*68 + h)*68 + (unsigned)ww)*256u + (unsigned)lc * 8u;
        bdst[j]  = (void*)&Bs[(w*4 + j) * 512];
    }

    const int l15 = lane & 15, lg = lane >> 4;
    const int m_w0 = (w & 1) * 64;
    const int n_w0 = (w >> 1) * 64;
    int rowA[4], rowB[4], chunkoff[2];
    #pragma unroll
    for (int i = 0; i < 4; ++i) {
        rowA[i] = (m_w0 + i*16 + l15) * 128;
        rowB[i] = (n_w0 + i*16 + l15) * 128;
    }
    #pragma unroll
    for (int ks = 0; ks < 2; ++ks)
        chunkoff[ks] = ((4*ks + lg) ^ (lane & 7)) * 16;

    f32x4 acc[4][4];
    #pragma unroll
    for (int i = 0; i < 4; ++i)
        #pragma unroll
        for (int j = 0; j < 4; ++j)
            acc[i][j] = (f32x4){0.f, 0.f, 0.f, 0.f};

    for (int it = 0; it < cnt; ++it) {
        const int kt = t_start + it;
        const int k0 = kt << 6;
        const int t  = k0 >> 8;
        const int c0 = k0 & 255;
        const int ti = (t * 37) >> 8;
        const int tj = t - ti * 7;
        const unsigned aof = (unsigned)k0;
        const unsigned bof = (unsigned)(ti*68 + tj) * 512u + (unsigned)c0;

        #pragma unroll
        for (int j = 0; j < 4; ++j) gll16(Wbf + aoffs[j] + aof, adst[j]);
        #pragma unroll
        for (int j = 0; j < 4; ++j) gll16(XT + boffs[j] + bof, bdst[j]);

        __syncthreads();

        #pragma unroll
        for (int ks = 0; ks < 2; ++ks) {
            const int co = chunkoff[ks];
            bf16x8 av[4], bv[4];
            #pragma unroll
            for (int i = 0; i < 4; ++i)
                av[i] = *(const bf16x8*)((const char*)As + rowA[i] + co);
            #pragma unroll
            for (int i = 0; i < 4; ++i)
                bv[i] = *(const bf16x8*)((const char*)Bs + rowB[i] + co);
            #pragma unroll
            for (int i = 0; i < 4; ++i)
                #pragma unroll
                for (int j = 0; j < 4; ++j)
                    acc[i][j] = __builtin_amdgcn_mfma_f32_16x16x32_bf16(av[i], bv[j], acc[i][j], 0, 0, 0);
        }
        __syncthreads();
    }

    #pragma unroll
    for (int j = 0; j < 4; ++j) {
        const int n = n0 + n_w0 + j*16 + l15;
        const int b = n / HW;
        const int p = n - b * HW;
        #pragma unroll
        for (int i = 0; i < 4; ++i) {
            const int m = m_w0 + i*16 + lg*4;
            float* dst = out + ((size_t)(b*128 + m) * HW + p);
            dst[0]      = acc[i][j][0];
            dst[HW]     = acc[i][j][1];
            dst[2*HW]   = acc[i][j][2];
            dst[3*HW]   = acc[i][j][3];
        }
    }
}

// ---------------- fused combine + w2: attention logits from K-split partials ----------------
// thread = one position; sum 5 partials per oc, bias+relu, accumulate 49 logits in regs.
__global__ __launch_bounds__(256) void k_logits(
    const float* __restrict__ p0, const float* __restrict__ p1,
    const float* __restrict__ p2, const float* __restrict__ p3,
    const float* __restrict__ p4, const float* __restrict__ b1,
    const float* __restrict__ w2, const float* __restrict__ b2,
    float* __restrict__ out)
{
    __shared__ float w2s[NT * 128];
    __shared__ float b1s[128];
    __shared__ float b2s[NT];
    const int tid = threadIdx.x;
    for (int i = tid; i < NT * 128; i += 256) w2s[i] = w2[i];
    if (tid < 128) b1s[tid] = b1[tid];
    if (tid < NT)  b2s[tid] = b2[tid];
    __syncthreads();

    const int gidx = blockIdx.x * 256 + tid;    // exactly 12544
    const int b = gidx / HW;
    const int p = gidx - b * HW;
    const size_t u = (size_t)b * 128 * HW + p;

    float lg[NT];
    #pragma unroll
    for (int t = 0; t < NT; ++t) lg[t] = b2s[t];

    for (int oc = 0; oc < 128; ++oc) {
        const size_t a = u + (size_t)oc * HW;
        float v = p0[a] + p1[a] + p2[a] + p3[a] + p4[a] + b1s[oc];
        v = fmaxf(v, 0.f);
        const float* wrow = w2s + oc;
        #pragma unroll
        for (int t = 0; t < NT; ++t)
            lg[t] = fmaf(wrow[t * 128], v, lg[t]);
    }
    float* dst = out + (size_t)b * NT * HW + p;
    #pragma unroll
    for (int t = 0; t < NT; ++t) dst[(size_t)t * HW] = lg[t];
}

// ---------------- BN batch stats ----------------
__global__ __launch_bounds__(256) void k_bnstats(const float* __restrict__ X, int nch,
                                                 float* __restrict__ meanOut,
                                                 float* __restrict__ rstdOut)
{
    const int ch  = blockIdx.x;
    const int tid = threadIdx.x;
    float s1 = 0.f, s2 = 0.f;
    for (int b = 0; b < 4; ++b) {
        const float* base = X + ((size_t)b * nch + ch) * HW;
        for (int p = tid; p < HW; p += 256) { float v = base[p]; s1 += v; s2 += v * v; }
    }
    for (int off = 32; off > 0; off >>= 1) {
        s1 += __shfl_down(s1, off);
        s2 += __shfl_down(s2, off);
    }
    __shared__ float r1[4], r2[4];
    const int lane = tid & 63, wv = tid >> 6;
    if (lane == 0) { r1[wv] = s1; r2[wv] = s2; }
    __syncthreads();
    if (tid == 0) {
        float a = r1[0] + r1[1] + r1[2] + r1[3];
        float q = r2[0] + r2[1] + r2[2] + r2[3];
        float mean = a * (1.f / 12544.f);
        float var  = q * (1.f / 12544.f) - mean * mean;
        meanOut[ch] = mean;
        rstdOut[ch] = rsqrtf(var + 1e-5f);
    }
}

// ---------------- fused BN + relu + softmax over 49 channels (in place) ----------------
__global__ __launch_bounds__(256) void k_bnsoftmax(float* __restrict__ X,
        const float* __restrict__ mean, const float* __restrict__ rstd,
        const float* __restrict__ gam,  const float* __restrict__ bet)
{
    const int gidx = blockIdx.x * 256 + threadIdx.x;
    const int b = gidx / HW;
    const int p = gidx - b * HW;
    float* base = X + (size_t)b * NT * HW + p;
    float vals[NT];
    float m = -1e30f;
    #pragma unroll
    for (int t = 0; t < NT; ++t) {
        float v = base[(size_t)t * HW];
        v = (v - mean[t]) * rstd[t] * gam[t] + bet[t];
        v = fmaxf(v, 0.f);
        vals[t] = v;
        m = fmaxf(m, v);
    }
    float s = 0.f;
    #pragma unroll
    for (int t = 0; t < NT; ++t) { float e = __expf(vals[t] - m); vals[t] = e; s += e; }
    const float inv = 1.f / s;
    #pragma unroll
    for (int t = 0; t < NT; ++t) base[(size_t)t * HW] = vals[t] * inv;
}

// ---------------- attention apply v2: register-blocked, LDS-free (validated) ----------------
__global__ __launch_bounds__(256) void k_attapply2(const float* __restrict__ Xpad,
        const float* __restrict__ att, float* __restrict__ Y)
{
    const int tid  = threadIdx.x;
    const int wv   = tid >> 6;
    const int lane = tid & 63;
    const int wq   = lane & 15;          // active < 14
    const int rs   = lane >> 4;
    const int rq   = blockIdx.x;         // 0..13
    const int cg   = blockIdx.y;         // 0..63
    const int b    = blockIdx.z;         // 0..3
    const int c    = cg * 4 + wv;
    const int h    = rq * 4 + rs;
    const int w0   = min(wq, 13) * 4;

    const float* xbase = Xpad + ((size_t)(b*256 + c) * 68 + h) * 68 + w0;
    const float* abase = att + (size_t)b * NT * HW + h * 56 + w0;
    float4 acc = {0.f, 0.f, 0.f, 0.f};
    #pragma unroll
    for (int ti = 0; ti < 7; ++ti) {
        const float* xr = xbase + ti * 136;          // row h + 2*ti
        float xf[16];
        *(float4*)&xf[0]  = *(const float4*)(xr);
        *(float4*)&xf[4]  = *(const float4*)(xr + 4);
        *(float4*)&xf[8]  = *(const float4*)(xr + 8);
        *(float4*)&xf[12] = *(const float4*)(xr + 12);
        #pragma unroll
        for (int tj = 0; tj < 7; ++tj) {
            const float4 a4 = *(const float4*)(abase + (size_t)(ti*7 + tj) * HW);
            acc.x = fmaf(xf[2*tj + 0], a4.x, acc.x);
            acc.y = fmaf(xf[2*tj + 1], a4.y, acc.y);
            acc.z = fmaf(xf[2*tj + 2], a4.z, acc.z);
            acc.w = fmaf(xf[2*tj + 3], a4.w, acc.w);
        }
    }
    if (wq < 14)
        *(float4*)(Y + (size_t)(b*256 + c) * HW + h * 56 + w0) = acc;
}

// ---------------- fused final BN + relu -> dec_out, + sigmoid(c3) -> side ----------------
__global__ __launch_bounds__(256) void k_bnside(const float* __restrict__ X,
        const float* __restrict__ mean, const float* __restrict__ rstd,
        const float* __restrict__ gam,  const float* __restrict__ bet,
        const float* __restrict__ w3,   const float* __restrict__ b3,
        float* __restrict__ dec_out,    float* __restrict__ side)
{
    __shared__ float ms[128], rs[128], gs[128], bs[128], w3s[128];
    const int tid = threadIdx.x;
    if (tid < 128) {
        ms[tid] = mean[tid]; rs[tid] = rstd[tid];
        gs[tid] = gam[tid];  bs[tid] = bet[tid];
        w3s[tid] = w3[tid];
    }
    __syncthreads();
    const int gidx = blockIdx.x * 256 + tid;    // exactly 12544
    const int b = gidx / HW;
    const int p = gidx - b * HW;
    const size_t u = (size_t)b * 128 * HW + p;
    float acc = b3[0];
    #pragma unroll 8
    for (int c = 0; c < 128; ++c) {
        const size_t a = u + (size_t)c * HW;
        float v = (X[a] - ms[c]) * rs[c] * gs[c] + bs[c];
        v = fmaxf(v, 0.f);
        dec_out[a] = v;
        acc = fmaf(v, w3s[c], acc);
    }
    side[gidx] = 1.f / (1.f + __expf(-acc));
}

// ---------------- launcher ----------------
extern "C" void kernel_launch(void* const* d_in, const int* in_sizes, int n_in,
                              void* d_out, int out_size, void* d_ws, size_t ws_size,
                              hipStream_t stream)
{
    const float* en  = (const float*)d_in[0];
    const float* dec = (const float*)d_in[1];
    const float* w1  = (const float*)d_in[2];
    const float* b1  = (const float*)d_in[3];
    const float* w2  = (const float*)d_in[4];
    const float* b2  = (const float*)d_in[5];
    const float* bng = (const float*)d_in[6];
    const float* bnb = (const float*)d_in[7];
    const float* c1w = (const float*)d_in[8];
    const float* c1b = (const float*)d_in[9];
    const float* c2w = (const float*)d_in[10];
    const float* c2b = (const float*)d_in[11];
    const float* bfg = (const float*)d_in[12];
    const float* bfb = (const float*)d_in[13];
    const float* c3w = (const float*)d_in[14];
    const float* c3b = (const float*)d_in[15];

    float* ws = (float*)d_ws;                   // 20,750,848 floats (proven extent)
    float* dec_up   = ws + R0;
    float* part0    = ws + R0;
    float* part1    = ws + R0 + 1605632u;
    float* fmap_att = ws + R0;
    float* attb     = ws + R1;                            // old fmap slot
    float* xpad     = ws + R2;
    __hip_bfloat16* c2wb = (__hip_bfloat16*)(ws + R3);
    __hip_bfloat16* xcat = (__hip_bfloat16*)(ws + R4);    // dead before part2/3 written
    float* part2    = ws + R4;
    float* part3    = ws + R4 + 1605632u;
    float* x2       = ws + R4;
    __hip_bfloat16* attT = (__hip_bfloat16*)(ws + R4 + 1605632u);  // part3 slot
    __hip_bfloat16* c1wb = (__hip_bfloat16*)(ws + R5);    // dead before part4 written
    float* part4    = ws + R5;
    float* stats    = ws + R6;
    __hip_bfloat16* xpadT = (__hip_bfloat16*)(ws + R7);
    __hip_bfloat16* wbf   = (__hip_bfloat16*)(ws + R8);

    float* dec_out = (float*)d_out;
    float* side    = (float*)d_out + 1605632u;

    // 0. zero padded buffers (borders must be 0 every call; interiors overwritten by gemmc1)
    hipMemsetAsync(xpad,  0, (size_t)4 * 256 * PADA * sizeof(float), stream);
    hipMemsetAsync(xpadT, 0, (size_t)4 * PADA * 256 * sizeof(__hip_bfloat16), stream);
    // 1. bilinear upsample dec -> dec_up
    k_upsample<<<dim3(12544), dim3(256), 0, stream>>>(dec, dec_up);
    // 2-3. build xcat NHWC bf16 [4][3136][512] = [en ; dec_up]
    k_t2nhwc<<<dim3(49, 4, 4), dim3(256), 0, stream>>>(en, xcat, 512, 0);
    k_t2nhwc<<<dim3(49, 4, 4), dim3(256), 0, stream>>>(dec_up, xcat, 512, 256);
    // 4. c1 weight -> bf16
    k_cvt<<<dim3(512), dim3(256), 0, stream>>>(c1w, c1wb);
    // 5. relu(c1 x xcat) via MFMA -> xpad (fp32) + xpadT (bf16), fmap eliminated
    k_gemmc1<<<dim3(98, 2), dim3(256), 0, stream>>>(c1wb, xcat, c1b, xpad, xpadT);
    // 6. w1 -> bf16 [oc][t*256+c] (LDS transpose)
    k_w1bf2<<<dim3(128), dim3(256), 0, stream>>>(w1, wbf);
    // 7. big dilated conv (K-split x5)
    k_convmfma<<<dim3(98, 5), dim3(256), 0, stream>>>(wbf, xpadT, part0, part1, part2, part3, part4);
    // 8. fused combine + w2 -> attention logits (k1 eliminated)
    k_logits<<<dim3(49), dim3(256), 0, stream>>>(part0, part1, part2, part3, part4, b1, w2, b2, attb);
    // 9-10. BN stats + BN/relu/softmax
    k_bnstats<<<dim3(49), dim3(256), 0, stream>>>(attb, 49, stats + 0, stats + 64);
    k_bnsoftmax<<<dim3(49), dim3(256), 0, stream>>>(attb, stats + 0, stats + 64, bng, bnb);
    // 11. local attention gather -> fmap_att
    k_attapply2<<<dim3(14, 64, 4), dim3(256), 0, stream>>>(xpad, attb, fmap_att);
    // 12. fmap_att -> attT NHWC bf16
    k_t2nhwc<<<dim3(49, 4, 4), dim3(256), 0, stream>>>(fmap_att, attT, 256, 0);
    // 13. c2 weight -> bf16
    k_cvt<<<dim3(256), dim3(256), 0, stream>>>(c2w, c2wb);
    // 14. x2 = c2 x [xpadT(center) ; attT] via MFMA
    k_gemmc2<<<dim3(98), dim3(256), 0, stream>>>(c2wb, xpadT, attT, c2b, x2);
    // 15. BN stats over x2
    k_bnstats<<<dim3(128), dim3(256), 0, stream>>>(x2, 128, stats + 128, stats + 256);
    // 16. fused BN/relu -> dec_out + sigmoid side (side re-read eliminated)
    k_bnside<<<dim3(49), dim3(256), 0, stream>>>(x2, stats + 128, stats + 256, bfg, bfb,
                                                 c3w, c3b, dec_out, side);
}

// Round 8
// 227.037 us; speedup vs baseline: 1.1739x; 1.1739x over previous
//
#include <hip/hip_runtime.h>
#include <hip/hip_bf16.h>
#include <math.h>

// ---------------- problem constants ----------------
#define HW    3136        // 56*56
#define PADA  4624        // 68*68 padded plane (fp32 NCHW)
#define NT    49

// ---------------- workspace regions (float offsets) — proven extent ----------------
// R0: dec_up -> part0,part1 -> fmap_att
// R1: attb [4][49][3136]
// R2: xpad fp32 [4][256][68][68]
// R3: k1 -> c2wb bf16 (after w2-gemm consumed k1)
// R4: xcat bf16 -> part2,part3 -> x2 (+ attT bf16 in part3 slot)
// R5: c1wb bf16 -> part4
// R6: stats
// R7: xpadT bf16 [4][68][68][256]
// R8: wbf bf16 [128][12544]
#define R0 0u
#define R1 3211264u
#define R2 6422528u
#define R3 11157504u
#define R4 12763136u
#define R5 15974400u
#define R6 17580032u
#define R7 17580544u
#define R8 19948032u

typedef __attribute__((ext_vector_type(8))) short bf16x8;
typedef __attribute__((ext_vector_type(4))) float f32x4;

__device__ __forceinline__ void gll16(const void* g, void* l) {
    __builtin_amdgcn_global_load_lds((const __attribute__((address_space(1))) void*)g,
                                     (__attribute__((address_space(3))) void*)l, 16, 0, 0);
}

// ---------------- bilinear 2x upsample (align_corners=False) ----------------
__global__ void k_upsample(const float* __restrict__ src, float* __restrict__ dst)
{
    int j = blockIdx.x * 256 + threadIdx.x;
    int bc = j / HW;
    int p  = j - bc * HW;
    int h  = p / 56;
    int w  = p - h * 56;

    int ih0; float fh;
    if (h & 1) { ih0 = h >> 1;       fh = 0.25f; }
    else       { ih0 = (h >> 1) - 1; fh = 0.75f; }
    int ih1 = min(ih0 + 1, 27); ih0 = max(ih0, 0);
    int iw0; float fw;
    if (w & 1) { iw0 = w >> 1;       fw = 0.25f; }
    else       { iw0 = (w >> 1) - 1; fw = 0.75f; }
    int iw1 = min(iw0 + 1, 27); iw0 = max(iw0, 0);

    const float* s = src + (size_t)bc * 784;
    float v00 = s[ih0*28 + iw0], v01 = s[ih0*28 + iw1];
    float v10 = s[ih1*28 + iw0], v11 = s[ih1*28 + iw1];
    dst[j] = (1.f-fh)*((1.f-fw)*v00 + fw*v01) + fh*((1.f-fw)*v10 + fw*v11);
}

// ---------------- tiled NCHW fp32 -> NHWC bf16 transpose (validated) ----------------
__global__ __launch_bounds__(256) void k_t2nhwc(const float* __restrict__ src,
        __hip_bfloat16* __restrict__ dst, int kstride, int c_off)
{
    __shared__ float t[64][65];
    const int tid = threadIdx.x;
    const int p0 = blockIdx.x * 64;
    const int c0 = blockIdx.y * 64;
    const int b  = blockIdx.z;
    const int pl = tid & 63, cr = tid >> 6;
    #pragma unroll
    for (int i = 0; i < 16; ++i) {
        const int c = c0 + i*4 + cr;
        t[i*4+cr][pl] = src[((size_t)(b*256 + c)) * HW + p0 + pl];
    }
    __syncthreads();
    const int cl = tid & 63, pr = tid >> 6;
    #pragma unroll
    for (int i = 0; i < 16; ++i) {
        const int p = p0 + i*4 + pr;
        dst[((size_t)(b*HW + p)) * kstride + c_off + c0 + cl] = __float2bfloat16(t[cl][i*4+pr]);
    }
}

// ---------------- fp32 -> bf16 straight convert ----------------
__global__ void k_cvt(const float* __restrict__ s, __hip_bfloat16* __restrict__ d)
{
    int j = blockIdx.x * 256 + threadIdx.x;
    d[j] = __float2bfloat16(s[j]);
}

// ---------------- w1 [128][256][49] -> Wbf [oc][k=t*256+c] bf16, LDS transpose ----------------
__global__ __launch_bounds__(256) void k_w1bf2(const float* __restrict__ w1,
        __hip_bfloat16* __restrict__ wt)
{
    __shared__ float t[NT * 257];
    const int tid = threadIdx.x;
    const int oc  = blockIdx.x;             // 128 blocks
    const float* src = w1 + (size_t)oc * 12544;
    #pragma unroll
    for (int i = 0; i < 49; ++i) {
        const int idx = i * 256 + tid;      // contiguous read over [c][t]
        const int c  = idx / 49;
        const int tt = idx - c * 49;
        t[tt * 257 + c] = src[idx];
    }
    __syncthreads();
    __hip_bfloat16* dst = wt + (size_t)oc * 12544;
    #pragma unroll
    for (int i = 0; i < 49; ++i)
        dst[i * 256 + tid] = __float2bfloat16(t[i * 257 + tid]);
}

// ---------------- fp32 8x8 FMA microtile (w2 gemm only) ----------------
__device__ __forceinline__ void tile_fma(const float (*As)[128], const float (*Bs)[128],
                                         float acc[8][8], int tx, int ty)
{
    #pragma unroll
    for (int kk = 0; kk < 16; ++kk) {
        const float4 a0 = *(const float4*)&As[kk][ty*8];
        const float4 a1 = *(const float4*)&As[kk][ty*8+4];
        const float4 b0 = *(const float4*)&Bs[kk][tx*8];
        const float4 b1 = *(const float4*)&Bs[kk][tx*8+4];
        const float av[8] = {a0.x,a0.y,a0.z,a0.w,a1.x,a1.y,a1.z,a1.w};
        const float bv[8] = {b0.x,b0.y,b0.z,b0.w,b1.x,b1.y,b1.z,b1.w};
        #pragma unroll
        for (int e = 0; e < 8; ++e)
            #pragma unroll
            for (int f = 0; f < 8; ++f)
                acc[e][f] = fmaf(av[e], bv[f], acc[e][f]);
    }
}

// ---------------- fp32 1x1 GEMM (w2 only: M=49, K=128) — validated ----------------
__global__ __launch_bounds__(256, 2) void k_gemm1x1(
    const float* __restrict__ W, const float* __restrict__ bias,
    const float* __restrict__ X0, int M, int K, float* __restrict__ Y)
{
    __shared__ float As[16][128];
    __shared__ float Bs[16][128];
    const int tid = threadIdx.x;
    const int tx = tid & 15, ty = tid >> 4;
    const int n0 = blockIdx.y * 128;

    const int amA = tid >> 2;
    const int kqA = tid & 3;
    const bool av0 = amA < M;
    const bool av1 = (amA + 64) < M;
    const size_t aoff0 = (size_t)amA * K + kqA * 4;
    const size_t aoff1 = (size_t)(amA + 64) * K + kqA * 4;

    const int colB = tid & 127;
    const int kkb  = tid >> 7;
    const int nB = n0 + colB;
    const int bB = nB / HW;
    const int pB = nB - bB * HW;
    const size_t u0 = (size_t)bB * K * HW + pB;

    float acc[8][8] = {};

    for (int k0 = 0; k0 < K; k0 += 16) {
        float4 va = av0 ? *(const float4*)(W + aoff0 + k0) : make_float4(0.f,0.f,0.f,0.f);
        float4 vb = av1 ? *(const float4*)(W + aoff1 + k0) : make_float4(0.f,0.f,0.f,0.f);
        As[kqA*4+0][amA] = va.x; As[kqA*4+1][amA] = va.y;
        As[kqA*4+2][amA] = va.z; As[kqA*4+3][amA] = va.w;
        As[kqA*4+0][amA+64] = vb.x; As[kqA*4+1][amA+64] = vb.y;
        As[kqA*4+2][amA+64] = vb.z; As[kqA*4+3][amA+64] = vb.w;
        #pragma unroll
        for (int e = 0; e < 8; ++e) {
            const int kk = e*2 + kkb;
            Bs[kk][colB] = X0[u0 + (size_t)(k0 + kk) * HW];
        }
        __syncthreads();
        tile_fma(As, Bs, acc, tx, ty);
        __syncthreads();
    }

    const int nE = n0 + tx*8;
    const int bE0 = nE / HW;
    const int pE0 = nE - bE0 * HW;
    #pragma unroll
    for (int e = 0; e < 8; ++e) {
        const int m = ty*8 + e;
        if (m < M) {
            const float bsv = bias[m];
            int b = bE0, p = pE0;
            #pragma unroll
            for (int f = 0; f < 8; ++f) {
                Y[((size_t)b * M + m) * HW + p] = acc[e][f] + bsv;
                if (++p == HW) { p = 0; ++b; }
            }
        }
    }
}

// ---------------- c1 MFMA GEMM: epilogue writes xpad (fp32) + xpadT (bf16) — validated R7 ----------------
__global__ __launch_bounds__(256, 2) void k_gemmc1(
    const __hip_bfloat16* __restrict__ A, const __hip_bfloat16* __restrict__ B0,
    const float* __restrict__ bias, float* __restrict__ Xpad,
    __hip_bfloat16* __restrict__ XpadT)
{
    __shared__ __hip_bfloat16 As[8192];
    __shared__ __hip_bfloat16 Bs[8192];
    const int tid  = threadIdx.x;
    const int w    = tid >> 6;
    const int lane = tid & 63;
    const int n0   = blockIdx.x * 128;
    const int m0   = blockIdx.y * 128;

    unsigned aoffs[4], boffs[4];
    void *adst[4], *bdst[4];
    #pragma unroll
    for (int j = 0; j < 4; ++j) {
        const int slot = (w*4 + j)*64 + lane;
        const int row  = slot >> 3;
        const int q    = slot & 7;
        const int lc   = q ^ (row & 7);
        aoffs[j] = (unsigned)(m0 + row) * 512u + (unsigned)lc * 8u;
        adst[j]  = (void*)&As[(w*4 + j) * 512];
        boffs[j] = (unsigned)(n0 + row) * 512u + (unsigned)lc * 8u;
        bdst[j]  = (void*)&Bs[(w*4 + j) * 512];
    }

    const int l15 = lane & 15, lg = lane >> 4;
    const int m_w0 = (w & 1) * 64;
    const int n_w0 = (w >> 1) * 64;
    int rowA[4], rowB[4], chunkoff[2];
    #pragma unroll
    for (int i = 0; i < 4; ++i) {
        rowA[i] = (m_w0 + i*16 + l15) * 128;
        rowB[i] = (n_w0 + i*16 + l15) * 128;
    }
    #pragma unroll
    for (int ks = 0; ks < 2; ++ks)
        chunkoff[ks] = ((4*ks + lg) ^ (lane & 7)) * 16;

    f32x4 acc[4][4];
    #pragma unroll
    for (int i = 0; i < 4; ++i)
        #pragma unroll
        for (int j = 0; j < 4; ++j)
            acc[i][j] = (f32x4){0.f, 0.f, 0.f, 0.f};

    for (int k0 = 0; k0 < 512; k0 += 64) {
        #pragma unroll
        for (int j = 0; j < 4; ++j) gll16(A + aoffs[j] + k0, adst[j]);
        #pragma unroll
        for (int j = 0; j < 4; ++j) gll16(B0 + boffs[j] + k0, bdst[j]);
        __syncthreads();
        #pragma unroll
        for (int ks = 0; ks < 2; ++ks) {
            const int co = chunkoff[ks];
            bf16x8 av[4], bv[4];
            #pragma unroll
            for (int i = 0; i < 4; ++i)
                av[i] = *(const bf16x8*)((const char*)As + rowA[i] + co);
            #pragma unroll
            for (int i = 0; i < 4; ++i)
                bv[i] = *(const bf16x8*)((const char*)Bs + rowB[i] + co);
            #pragma unroll
            for (int i = 0; i < 4; ++i)
                #pragma unroll
                for (int j = 0; j < 4; ++j)
                    acc[i][j] = __builtin_amdgcn_mfma_f32_16x16x32_bf16(av[i], bv[j], acc[i][j], 0, 0, 0);
        }
        __syncthreads();
    }

    #pragma unroll
    for (int j = 0; j < 4; ++j) {
        const int n = n0 + n_w0 + j*16 + l15;
        const int b = n / HW;
        const int p = n - b * HW;
        const int h = p / 56;
        const int ww = p - h * 56;
        #pragma unroll
        for (int i = 0; i < 4; ++i) {
            const int m = m0 + m_w0 + i*16 + lg*4;
            const float4 bs4 = *(const float4*)&bias[m];
            float v0 = fmaxf(acc[i][j][0] + bs4.x, 0.f);
            float v1 = fmaxf(acc[i][j][1] + bs4.y, 0.f);
            float v2 = fmaxf(acc[i][j][2] + bs4.z, 0.f);
            float v3 = fmaxf(acc[i][j][3] + bs4.w, 0.f);
            float* dp = Xpad + ((size_t)(b*256 + m)) * PADA + (h + 6) * 68 + (ww + 6);
            dp[0]      = v0;
            dp[PADA]   = v1;
            dp[2*PADA] = v2;
            dp[3*PADA] = v3;
            ushort4 pk;
            pk.x = __bfloat16_as_ushort(__float2bfloat16(v0));
            pk.y = __bfloat16_as_ushort(__float2bfloat16(v1));
            pk.z = __bfloat16_as_ushort(__float2bfloat16(v2));
            pk.w = __bfloat16_as_ushort(__float2bfloat16(v3));
            *(ushort4*)(XpadT + ((size_t)((b*68 + h + 6)*68 + ww + 6)) * 256 + m) = pk;
        }
    }
}

// ---------------- c2 MFMA GEMM (validated) ----------------
__global__ __launch_bounds__(256, 2) void k_gemmc2(
    const __hip_bfloat16* __restrict__ A, const __hip_bfloat16* __restrict__ XT,
    const __hip_bfloat16* __restrict__ AT, const float* __restrict__ bias,
    float* __restrict__ Y)
{
    __shared__ __hip_bfloat16 As[8192];
    __shared__ __hip_bfloat16 Bs[8192];
    const int tid  = threadIdx.x;
    const int w    = tid >> 6;
    const int lane = tid & 63;
    const int n0   = blockIdx.x * 128;

    unsigned aoffs[4], boffs0[4], boffs1[4];
    void *adst[4], *bdst[4];
    #pragma unroll
    for (int j = 0; j < 4; ++j) {
        const int slot = (w*4 + j)*64 + lane;
        const int row  = slot >> 3;
        const int q    = slot & 7;
        const int lc   = q ^ (row & 7);
        aoffs[j] = (unsigned)row * 512u + (unsigned)lc * 8u;
        adst[j]  = (void*)&As[(w*4 + j) * 512];
        const int n = n0 + row;
        const int b = n / HW;
        const int p = n - b * HW;
        const int h = p / 56;
        const int ww = p - h * 56;
        boffs0[j] = ((unsigned)(b*68 + h + 6)*68 + (unsigned)(ww + 6))*256u + (unsigned)lc * 8u;
        boffs1[j] = (unsigned)n * 256u + (unsigned)lc * 8u;
        bdst[j]  = (void*)&Bs[(w*4 + j) * 512];
    }

    const int l15 = lane & 15, lg = lane >> 4;
    const int m_w0 = (w & 1) * 64;
    const int n_w0 = (w >> 1) * 64;
    int rowA[4], rowB[4], chunkoff[2];
    #pragma unroll
    for (int i = 0; i < 4; ++i) {
        rowA[i] = (m_w0 + i*16 + l15) * 128;
        rowB[i] = (n_w0 + i*16 + l15) * 128;
    }
    #pragma unroll
    for (int ks = 0; ks < 2; ++ks)
        chunkoff[ks] = ((4*ks + lg) ^ (lane & 7)) * 16;

    f32x4 acc[4][4];
    #pragma unroll
    for (int i = 0; i < 4; ++i)
        #pragma unroll
        for (int j = 0; j < 4; ++j)
            acc[i][j] = (f32x4){0.f, 0.f, 0.f, 0.f};

    for (int k0 = 0; k0 < 512; k0 += 64) {
        #pragma unroll
        for (int j = 0; j < 4; ++j) gll16(A + aoffs[j] + k0, adst[j]);
        if (k0 < 256) {
            #pragma unroll
            for (int j = 0; j < 4; ++j) gll16(XT + boffs0[j] + k0, bdst[j]);
        } else {
            #pragma unroll
            for (int j = 0; j < 4; ++j) gll16(AT + boffs1[j] + (k0 - 256), bdst[j]);
        }
        __syncthreads();
        #pragma unroll
        for (int ks = 0; ks < 2; ++ks) {
            const int co = chunkoff[ks];
            bf16x8 av[4], bv[4];
            #pragma unroll
            for (int i = 0; i < 4; ++i)
                av[i] = *(const bf16x8*)((const char*)As + rowA[i] + co);
            #pragma unroll
            for (int i = 0; i < 4; ++i)
                bv[i] = *(const bf16x8*)((const char*)Bs + rowB[i] + co);
            #pragma unroll
            for (int i = 0; i < 4; ++i)
                #pragma unroll
                for (int j = 0; j < 4; ++j)
                    acc[i][j] = __builtin_amdgcn_mfma_f32_16x16x32_bf16(av[i], bv[j], acc[i][j], 0, 0, 0);
        }
        __syncthreads();
    }

    #pragma unroll
    for (int j = 0; j < 4; ++j) {
        const int n = n0 + n_w0 + j*16 + l15;
        const int b = n / HW;
        const int p = n - b * HW;
        #pragma unroll
        for (int i = 0; i < 4; ++i) {
            const int m = m_w0 + i*16 + lg*4;
            const float4 bs4 = *(const float4*)&bias[m];
            float* dst = Y + ((size_t)(b*128 + m) * HW + p);
            dst[0]    = acc[i][j][0] + bs4.x;
            dst[HW]   = acc[i][j][1] + bs4.y;
            dst[2*HW] = acc[i][j][2] + bs4.z;
            dst[3*HW] = acc[i][j][3] + bs4.w;
        }
    }
}

// ---------------- dilated 7x7 conv: bf16 MFMA implicit GEMM, K-split x5 (validated) ----------------
__global__ __launch_bounds__(256, 2) void k_convmfma(
    const __hip_bfloat16* __restrict__ Wbf, const __hip_bfloat16* __restrict__ XT,
    float* __restrict__ o0, float* __restrict__ o1, float* __restrict__ o2,
    float* __restrict__ o3, float* __restrict__ o4)
{
    __shared__ __hip_bfloat16 As[8192];
    __shared__ __hip_bfloat16 Bs[8192];
    const int tid  = threadIdx.x;
    const int w    = tid >> 6;
    const int lane = tid & 63;
    const int n0   = blockIdx.x * 128;
    const int s    = blockIdx.y;
    const int t_start = (s < 4) ? s * 40 : 158;
    const int cnt     = (s < 3) ? 40 : 38;
    float* __restrict__ out = (s==0)?o0:(s==1)?o1:(s==2)?o2:(s==3)?o3:o4;

    unsigned aoffs[4], boffs[4];
    void *adst[4], *bdst[4];
    #pragma unroll
    for (int j = 0; j < 4; ++j) {
        const int slot = (w*4 + j)*64 + lane;
        const int row  = slot >> 3;
        const int q    = slot & 7;
        const int lc   = q ^ (row & 7);
        aoffs[j] = (unsigned)row * 12544u + (unsigned)lc * 8u;
        adst[j]  = (void*)&As[(w*4 + j) * 512];
        const int n = n0 + row;
        const int b = n / HW;
        const int p = n - b * HW;
        const int h = p / 56;
        const int ww = p - h * 56;
        boffs[j] = ((unsigned)(b*68 + h)*68 + (unsigned)ww)*256u + (unsigned)lc * 8u;
        bdst[j]  = (void*)&Bs[(w*4 + j) * 512];
    }

    const int l15 = lane & 15, lg = lane >> 4;
    const int m_w0 = (w & 1) * 64;
    const int n_w0 = (w >> 1) * 64;
    int rowA[4], rowB[4], chunkoff[2];
    #pragma unroll
    for (int i = 0; i < 4; ++i) {
        rowA[i] = (m_w0 + i*16 + l15) * 128;
        rowB[i] = (n_w0 + i*16 + l15) * 128;
    }
    #pragma unroll
    for (int ks = 0; ks < 2; ++ks)
        chunkoff[ks] = ((4*ks + lg) ^ (lane & 7)) * 16;

    f32x4 acc[4][4];
    #pragma unroll
    for (int i = 0; i < 4; ++i)
        #pragma unroll
        for (int j = 0; j < 4; ++j)
            acc[i][j] = (f32x4){0.f, 0.f, 0.f, 0.f};

    for (int it = 0; it < cnt; ++it) {
        const int kt = t_start + it;
        const int k0 = kt << 6;
        const int t  = k0 >> 8;
        const int c0 = k0 & 255;
        const int ti = (t * 37) >> 8;
        const int tj = t - ti * 7;
        const unsigned aof = (unsigned)k0;
        const unsigned bof = (unsigned)(ti*68 + tj) * 512u + (unsigned)c0;

        #pragma unroll
        for (int j = 0; j < 4; ++j) gll16(Wbf + aoffs[j] + aof, adst[j]);
        #pragma unroll
        for (int j = 0; j < 4; ++j) gll16(XT + boffs[j] + bof, bdst[j]);

        __syncthreads();

        #pragma unroll
        for (int ks = 0; ks < 2; ++ks) {
            const int co = chunkoff[ks];
            bf16x8 av[4], bv[4];
            #pragma unroll
            for (int i = 0; i < 4; ++i)
                av[i] = *(const bf16x8*)((const char*)As + rowA[i] + co);
            #pragma unroll
            for (int i = 0; i < 4; ++i)
                bv[i] = *(const bf16x8*)((const char*)Bs + rowB[i] + co);
            #pragma unroll
            for (int i = 0; i < 4; ++i)
                #pragma unroll
                for (int j = 0; j < 4; ++j)
                    acc[i][j] = __builtin_amdgcn_mfma_f32_16x16x32_bf16(av[i], bv[j], acc[i][j], 0, 0, 0);
        }
        __syncthreads();
    }

    #pragma unroll
    for (int j = 0; j < 4; ++j) {
        const int n = n0 + n_w0 + j*16 + l15;
        const int b = n / HW;
        const int p = n - b * HW;
        #pragma unroll
        for (int i = 0; i < 4; ++i) {
            const int m = m_w0 + i*16 + lg*4;
            float* dst = out + ((size_t)(b*128 + m) * HW + p);
            dst[0]      = acc[i][j][0];
            dst[HW]     = acc[i][j][1];
            dst[2*HW]   = acc[i][j][2];
            dst[3*HW]   = acc[i][j][3];
        }
    }
}

// ---------------- combine K-split partials + bias + relu -> k1 (validated) ----------------
__global__ void k_combine(const float* __restrict__ p0, const float* __restrict__ p1,
                          const float* __restrict__ p2, const float* __restrict__ p3,
                          const float* __restrict__ p4, const float* __restrict__ bias,
                          float* __restrict__ Y)
{
    int j = blockIdx.x * 256 + threadIdx.x;
    int oc = (j / HW) & 127;
    float v = p0[j] + p1[j] + p2[j] + p3[j] + p4[j] + bias[oc];
    Y[j] = fmaxf(v, 0.f);
}

// ---------------- BN batch stats (validated) ----------------
__global__ __launch_bounds__(256) void k_bnstats(const float* __restrict__ X, int nch,
                                                 float* __restrict__ meanOut,
                                                 float* __restrict__ rstdOut)
{
    const int ch  = blockIdx.x;
    const int tid = threadIdx.x;
    float s1 = 0.f, s2 = 0.f;
    for (int b = 0; b < 4; ++b) {
        const float* base = X + ((size_t)b * nch + ch) * HW;
        for (int p = tid; p < HW; p += 256) { float v = base[p]; s1 += v; s2 += v * v; }
    }
    for (int off = 32; off > 0; off >>= 1) {
        s1 += __shfl_down(s1, off);
        s2 += __shfl_down(s2, off);
    }
    __shared__ float r1[4], r2[4];
    const int lane = tid & 63, wv = tid >> 6;
    if (lane == 0) { r1[wv] = s1; r2[wv] = s2; }
    __syncthreads();
    if (tid == 0) {
        float a = r1[0] + r1[1] + r1[2] + r1[3];
        float q = r2[0] + r2[1] + r2[2] + r2[3];
        float mean = a * (1.f / 12544.f);
        float var  = q * (1.f / 12544.f) - mean * mean;
        meanOut[ch] = mean;
        rstdOut[ch] = rsqrtf(var + 1e-5f);
    }
}

// ---------------- fused BN + relu + softmax over 49 channels (validated) ----------------
__global__ __launch_bounds__(256) void k_bnsoftmax(float* __restrict__ X,
        const float* __restrict__ mean, const float* __restrict__ rstd,
        const float* __restrict__ gam,  const float* __restrict__ bet)
{
    const int gidx = blockIdx.x * 256 + threadIdx.x;
    const int b = gidx / HW;
    const int p = gidx - b * HW;
    float* base = X + (size_t)b * NT * HW + p;
    float vals[NT];
    float m = -1e30f;
    #pragma unroll
    for (int t = 0; t < NT; ++t) {
        float v = base[(size_t)t * HW];
        v = (v - mean[t]) * rstd[t] * gam[t] + bet[t];
        v = fmaxf(v, 0.f);
        vals[t] = v;
        m = fmaxf(m, v);
    }
    float s = 0.f;
    #pragma unroll
    for (int t = 0; t < NT; ++t) { float e = __expf(vals[t] - m); vals[t] = e; s += e; }
    const float inv = 1.f / s;
    #pragma unroll
    for (int t = 0; t < NT; ++t) base[(size_t)t * HW] = vals[t] * inv;
}

// ---------------- attention apply v2: register-blocked, LDS-free (validated) ----------------
__global__ __launch_bounds__(256) void k_attapply2(const float* __restrict__ Xpad,
        const float* __restrict__ att, float* __restrict__ Y)
{
    const int tid  = threadIdx.x;
    const int wv   = tid >> 6;
    const int lane = tid & 63;
    const int wq   = lane & 15;          // active < 14
    const int rs   = lane >> 4;
    const int rq   = blockIdx.x;         // 0..13
    const int cg   = blockIdx.y;         // 0..63
    const int b    = blockIdx.z;         // 0..3
    const int c    = cg * 4 + wv;
    const int h    = rq * 4 + rs;
    const int w0   = min(wq, 13) * 4;

    const float* xbase = Xpad + ((size_t)(b*256 + c) * 68 + h) * 68 + w0;
    const float* abase = att + (size_t)b * NT * HW + h * 56 + w0;
    float4 acc = {0.f, 0.f, 0.f, 0.f};
    #pragma unroll
    for (int ti = 0; ti < 7; ++ti) {
        const float* xr = xbase + ti * 136;          // row h + 2*ti
        float xf[16];
        *(float4*)&xf[0]  = *(const float4*)(xr);
        *(float4*)&xf[4]  = *(const float4*)(xr + 4);
        *(float4*)&xf[8]  = *(const float4*)(xr + 8);
        *(float4*)&xf[12] = *(const float4*)(xr + 12);
        #pragma unroll
        for (int tj = 0; tj < 7; ++tj) {
            const float4 a4 = *(const float4*)(abase + (size_t)(ti*7 + tj) * HW);
            acc.x = fmaf(xf[2*tj + 0], a4.x, acc.x);
            acc.y = fmaf(xf[2*tj + 1], a4.y, acc.y);
            acc.z = fmaf(xf[2*tj + 2], a4.z, acc.z);
            acc.w = fmaf(xf[2*tj + 3], a4.w, acc.w);
        }
    }
    if (wq < 14)
        *(float4*)(Y + (size_t)(b*256 + c) * HW + h * 56 + w0) = acc;
}

// ---------------- fused final BN + relu -> dec_out, + sigmoid(c3) -> side (validated R7) ----------------
__global__ __launch_bounds__(256) void k_bnside(const float* __restrict__ X,
        const float* __restrict__ mean, const float* __restrict__ rstd,
        const float* __restrict__ gam,  const float* __restrict__ bet,
        const float* __restrict__ w3,   const float* __restrict__ b3,
        float* __restrict__ dec_out,    float* __restrict__ side)
{
    __shared__ float ms[128], rs[128], gs[128], bs[128], w3s[128];
    const int tid = threadIdx.x;
    if (tid < 128) {
        ms[tid] = mean[tid]; rs[tid] = rstd[tid];
        gs[tid] = gam[tid];  bs[tid] = bet[tid];
        w3s[tid] = w3[tid];
    }
    __syncthreads();
    const int gidx = blockIdx.x * 256 + tid;    // exactly 12544
    const int b = gidx / HW;
    const int p = gidx - b * HW;
    const size_t u = (size_t)b * 128 * HW + p;
    float acc = b3[0];
    #pragma unroll 8
    for (int c = 0; c < 128; ++c) {
        const size_t a = u + (size_t)c * HW;
        float v = (X[a] - ms[c]) * rs[c] * gs[c] + bs[c];
        v = fmaxf(v, 0.f);
        dec_out[a] = v;
        acc = fmaf(v, w3s[c], acc);
    }
    side[gidx] = 1.f / (1.f + __expf(-acc));
}

// ---------------- launcher ----------------
extern "C" void kernel_launch(void* const* d_in, const int* in_sizes, int n_in,
                              void* d_out, int out_size, void* d_ws, size_t ws_size,
                              hipStream_t stream)
{
    const float* en  = (const float*)d_in[0];
    const float* dec = (const float*)d_in[1];
    const float* w1  = (const float*)d_in[2];
    const float* b1  = (const float*)d_in[3];
    const float* w2  = (const float*)d_in[4];
    const float* b2  = (const float*)d_in[5];
    const float* bng = (const float*)d_in[6];
    const float* bnb = (const float*)d_in[7];
    const float* c1w = (const float*)d_in[8];
    const float* c1b = (const float*)d_in[9];
    const float* c2w = (const float*)d_in[10];
    const float* c2b = (const float*)d_in[11];
    const float* bfg = (const float*)d_in[12];
    const float* bfb = (const float*)d_in[13];
    const float* c3w = (const float*)d_in[14];
    const float* c3b = (const float*)d_in[15];

    float* ws = (float*)d_ws;                   // 20,750,848 floats (proven extent)
    float* dec_up   = ws + R0;
    float* part0    = ws + R0;
    float* part1    = ws + R0 + 1605632u;
    float* fmap_att = ws + R0;
    float* attb     = ws + R1;
    float* xpad     = ws + R2;
    float* k1       = ws + R3;
    __hip_bfloat16* c2wb = (__hip_bfloat16*)(ws + R3);    // overlays k1 AFTER w2-gemm consumed it
    __hip_bfloat16* xcat = (__hip_bfloat16*)(ws + R4);    // dead before part2/3 written
    float* part2    = ws + R4;
    float* part3    = ws + R4 + 1605632u;
    float* x2       = ws + R4;
    __hip_bfloat16* attT = (__hip_bfloat16*)(ws + R4 + 1605632u);  // part3 slot
    __hip_bfloat16* c1wb = (__hip_bfloat16*)(ws + R5);    // dead before part4 written
    float* part4    = ws + R5;
    float* stats    = ws + R6;
    __hip_bfloat16* xpadT = (__hip_bfloat16*)(ws + R7);
    __hip_bfloat16* wbf   = (__hip_bfloat16*)(ws + R8);

    float* dec_out = (float*)d_out;
    float* side    = (float*)d_out + 1605632u;

    // 0. zero padded buffers (borders must be 0 every call; interiors overwritten by gemmc1)
    hipMemsetAsync(xpad,  0, (size_t)4 * 256 * PADA * sizeof(float), stream);
    hipMemsetAsync(xpadT, 0, (size_t)4 * PADA * 256 * sizeof(__hip_bfloat16), stream);
    // 1. bilinear upsample dec -> dec_up
    k_upsample<<<dim3(12544), dim3(256), 0, stream>>>(dec, dec_up);
    // 2-3. build xcat NHWC bf16 [4][3136][512] = [en ; dec_up]
    k_t2nhwc<<<dim3(49, 4, 4), dim3(256), 0, stream>>>(en, xcat, 512, 0);
    k_t2nhwc<<<dim3(49, 4, 4), dim3(256), 0, stream>>>(dec_up, xcat, 512, 256);
    // 4. c1 weight -> bf16
    k_cvt<<<dim3(512), dim3(256), 0, stream>>>(c1w, c1wb);
    // 5. relu(c1 x xcat) via MFMA -> xpad (fp32) + xpadT (bf16)
    k_gemmc1<<<dim3(98, 2), dim3(256), 0, stream>>>(c1wb, xcat, c1b, xpad, xpadT);
    // 6. w1 -> bf16 [oc][t*256+c]
    k_w1bf2<<<dim3(128), dim3(256), 0, stream>>>(w1, wbf);
    // 7. big dilated conv (K-split x5)
    k_convmfma<<<dim3(98, 5), dim3(256), 0, stream>>>(wbf, xpadT, part0, part1, part2, part3, part4);
    // 8. combine -> k1 (validated two-stage logits path, reverting R7's k_logits)
    k_combine<<<dim3(6272), dim3(256), 0, stream>>>(part0, part1, part2, part3, part4, b1, k1);
    // 9. attention logits = w2 * k1 + b2 (fp32)
    k_gemm1x1<<<dim3(1, 98), dim3(256), 0, stream>>>(w2, b2, k1, 49, 128, attb);
    // 10-11. BN stats + BN/relu/softmax
    k_bnstats<<<dim3(49), dim3(256), 0, stream>>>(attb, 49, stats + 0, stats + 64);
    k_bnsoftmax<<<dim3(49), dim3(256), 0, stream>>>(attb, stats + 0, stats + 64, bng, bnb);
    // 12. local attention gather -> fmap_att
    k_attapply2<<<dim3(14, 64, 4), dim3(256), 0, stream>>>(xpad, attb, fmap_att);
    // 13. fmap_att -> attT NHWC bf16
    k_t2nhwc<<<dim3(49, 4, 4), dim3(256), 0, stream>>>(fmap_att, attT, 256, 0);
    // 14. c2 weight -> bf16 (k1 dead after step 9)
    k_cvt<<<dim3(256), dim3(256), 0, stream>>>(c2w, c2wb);
    // 15. x2 = c2 x [xpadT(center) ; attT] via MFMA
    k_gemmc2<<<dim3(98), dim3(256), 0, stream>>>(c2wb, xpadT, attT, c2b, x2);
    // 16. BN stats over x2
    k_bnstats<<<dim3(128), dim3(256), 0, stream>>>(x2, 128, stats + 128, stats + 256);
    // 17. fused BN/relu -> dec_out + sigmoid side
    k_bnside<<<dim3(49), dim3(256), 0, stream>>>(x2, stats + 128, stats + 256, bfg, bfb,
                                                 c3w, c3b, dec_out, side);
}